// Round 9
// baseline (353.526 us; speedup 1.0000x reference)
//
#include <hip/hip_runtime.h>
#include <hip/hip_bf16.h>
#include <cstdint>

#define BB 128
#define LL 28
#define FF 28
#define DM 256
#define DI 512
#define DS 16
#define DR 16
#define KK 3
#define NLAYER 5
#define NOUT 10
#define NDBC (DR + 2 * DS)  // 48

#define N_INW (NLAYER * 2 * DI * DM)   // 1310720
#define N_OPW (NLAYER * DM * DI)       // 655360
#define N_XPW (NLAYER * NDBC * DI)     // 122880

typedef __attribute__((ext_vector_type(8))) short bf16x8;
typedef __attribute__((ext_vector_type(4))) float f32x4;

__device__ __forceinline__ float sigmoidf_(float x) { return 1.0f / (1.0f + __expf(-x)); }
__device__ __forceinline__ float siluf_(float x) { return x * sigmoidf_(x); }
__device__ __forceinline__ float softplusf_(float x) {
    return (x > 20.0f) ? x : log1pf(expf(x));
}

// ---------------- weight cast fp32 -> bf16 (one kernel, all layers) ----------------
__global__ void cast_weights(const float* __restrict__ inw, const float* __restrict__ opw,
                             const float* __restrict__ xpw,
                             __hip_bfloat16* __restrict__ inwb, __hip_bfloat16* __restrict__ opwb,
                             __hip_bfloat16* __restrict__ xpwb) {
    int i = (blockIdx.x * 256 + threadIdx.x) * 4;
    const float* s; __hip_bfloat16* d; int off;
    if (i < N_INW) { s = inw; d = inwb; off = i; }
    else if (i < N_INW + N_OPW) { s = opw; d = opwb; off = i - N_INW; }
    else if (i < N_INW + N_OPW + N_XPW) { s = xpw; d = xpwb; off = i - N_INW - N_OPW; }
    else return;
    float4 v = *(const float4*)&s[off];
    d[off + 0] = __float2bfloat16(v.x);
    d[off + 1] = __float2bfloat16(v.y);
    d[off + 2] = __float2bfloat16(v.z);
    d[off + 3] = __float2bfloat16(v.w);
}

// ---------------- whole-network megakernel: 1 block = 1 batch element ----------------
// 512 threads = 8 waves. All activations LDS-resident; weights streamed from
// L2 (bf16, shared by all 128 blocks). MFMA fragment mappings identical to the
// round-6-verified gemm_mfma kernel (A-frag row=lane&15, k=(lane>>4)*8;
// C/D row=(lane>>4)*4+reg, col=lane&15).
__global__ __launch_bounds__(512, 2) void mamba_mega(
        const float* __restrict__ x,        // [BB][LL][FF]
        const float* __restrict__ ipw,      // [DM][FF]
        const float* __restrict__ convw,    // [NL][DI][KK]
        const float* __restrict__ convb,    // [NL][DI]
        const float* __restrict__ dtw,      // [NL][DI][DR]
        const float* __restrict__ dtb,      // [NL][DI]
        const float* __restrict__ alog,     // [NL][DI][DS]
        const float* __restrict__ Dvec,     // [NL][DI]
        const float* __restrict__ clsw,     // [NOUT][DM]
        const __hip_bfloat16* __restrict__ inwb,  // [NL][2*DI][DM]
        const __hip_bfloat16* __restrict__ opwb,  // [NL][DM][DI]
        const __hip_bfloat16* __restrict__ xpwb,  // [NL][NDBC][DI]
        float* __restrict__ out)            // [BB][NOUT]
{
    __shared__ float h32[LL][DM];                          // 28.7 KB  fp32 residual
    __shared__ __align__(16) __hip_bfloat16 hbf[32][264];  // 16.9 KB  bf16 h (M-pad 32, k-pad 8)
    __shared__ __align__(16) __hip_bfloat16 xb[32][520];   // 33.3 KB  conv input, then y
    __shared__ __align__(16) __hip_bfloat16 zb[LL][DI];    // 28.7 KB  gate input
    __shared__ __align__(16) __hip_bfloat16 ub[32][520];   // 33.3 KB  conv output
    __shared__ float dbc[32][NDBC];                        // 6.1 KB
    __shared__ float sx[LL][FF];                           // 3.1 KB
    __shared__ float pooled[DM];                           // 1 KB

    const int b = blockIdx.x;
    const int t = threadIdx.x;      // 0..511
    const int wave = t >> 6;
    const int lane = t & 63;
    const int rla = lane & 15;              // fragment row (A and B)
    const int koff = (lane >> 4) * 8;       // fragment k offset
    const int lrow = (lane >> 4) * 4;       // C/D row base
    const int lcol = lane & 15;             // C/D col

    // ---- zero M-pad rows (28..31) of hbf / xb / ub once; they stay zero ----
    for (int i = t; i < 4 * 264; i += 512) hbf[28 + i / 264][i % 264] = __float2bfloat16(0.f);
    for (int i = t; i < 4 * 520; i += 512) {
        xb[28 + i / 520][i % 520] = __float2bfloat16(0.f);
        ub[28 + i / 520][i % 520] = __float2bfloat16(0.f);
    }
    // ---- stage x[b] ----
    for (int i = t; i < LL * FF / 4; i += 512)
        *(float4*)&sx[0][i * 4] = *(const float4*)&x[(size_t)b * LL * FF + i * 4];
    __syncthreads();

    // ---- input projection: h[l][n] = sum_f x[l][f] * ipw[n][f] ----
    if (t < DM) {
        const int n = t;
        float w[FF];
        #pragma unroll
        for (int q = 0; q < FF / 4; ++q) {
            float4 v = *(const float4*)&ipw[n * FF + q * 4];
            w[q * 4 + 0] = v.x; w[q * 4 + 1] = v.y; w[q * 4 + 2] = v.z; w[q * 4 + 3] = v.w;
        }
        for (int l = 0; l < LL; ++l) {
            float a0 = 0.f, a1 = 0.f, a2 = 0.f, a3 = 0.f;
            #pragma unroll
            for (int f = 0; f < FF; f += 4) {
                a0 += w[f + 0] * sx[l][f + 0];
                a1 += w[f + 1] * sx[l][f + 1];
                a2 += w[f + 2] * sx[l][f + 2];
                a3 += w[f + 3] * sx[l][f + 3];
            }
            float v = (a0 + a1) + (a2 + a3);
            h32[l][n] = v;
            hbf[l][n] = __float2bfloat16(v);
        }
    }
    __syncthreads();

    for (int layer = 0; layer < NLAYER; ++layer) {
        const __hip_bfloat16* inw_l = inwb + (size_t)layer * 2 * DI * DM;
        const __hip_bfloat16* opw_l = opwb + (size_t)layer * DM * DI;
        const __hip_bfloat16* xpw_l = xpwb + (size_t)layer * NDBC * DI;

        // ---- phase 1: xz = h @ inw^T  (M=28->32, N=1024, K=256) ----
        for (int nt = wave; nt < 64; nt += 8) {
            const int n0 = nt * 16;
            f32x4 acc0 = {}, acc1 = {};
            #pragma unroll
            for (int ks = 0; ks < 8; ++ks) {
                const int k0 = ks * 32;
                bf16x8 bf = *(const bf16x8*)&inw_l[(size_t)(n0 + rla) * DM + k0 + koff];
                bf16x8 a0 = *(const bf16x8*)&hbf[rla][k0 + koff];
                bf16x8 a1 = *(const bf16x8*)&hbf[16 + rla][k0 + koff];
                acc0 = __builtin_amdgcn_mfma_f32_16x16x32_bf16(a0, bf, acc0, 0, 0, 0);
                acc1 = __builtin_amdgcn_mfma_f32_16x16x32_bf16(a1, bf, acc1, 0, 0, 0);
            }
            const int n = n0 + lcol;
            #pragma unroll
            for (int r = 0; r < 4; ++r) {
                const int m0 = lrow + r;          // 0..15, always valid
                const int m1 = 16 + lrow + r;     // 16..31, guard <28
                if (n < DI) {
                    xb[m0][n] = __float2bfloat16(acc0[r]);
                    if (m1 < LL) xb[m1][n] = __float2bfloat16(acc1[r]);
                } else {
                    zb[m0][n - DI] = __float2bfloat16(acc0[r]);
                    if (m1 < LL) zb[m1][n - DI] = __float2bfloat16(acc1[r]);
                }
            }
        }
        __syncthreads();

        // ---- phase 2: u = silu(conv(xb)+cb), thread = channel ----
        {
            const int ch = t;
            const float c0 = convw[(size_t)layer * DI * KK + ch * KK + 0];
            const float c1 = convw[(size_t)layer * DI * KK + ch * KK + 1];
            const float c2 = convw[(size_t)layer * DI * KK + ch * KK + 2];
            const float cbv = convb[layer * DI + ch];
            float xm2 = 0.f, xm1 = 0.f;
            for (int l = 0; l < LL; ++l) {
                const float x0 = __bfloat162float(xb[l][ch]);
                const float acc = cbv + c0 * xm2 + c1 * xm1 + c2 * x0;
                xm2 = xm1; xm1 = x0;
                ub[l][ch] = __float2bfloat16(siluf_(acc));
            }
        }
        __syncthreads();

        // ---- phase 3: dbc = u @ xpw^T  (M=28->32, N=48, K=512), waves 0..5 ----
        if (wave < 6) {
            const int mt = wave & 1;
            const int nt = wave >> 1;
            const int n0 = nt * 16;
            f32x4 acc = {};
            #pragma unroll
            for (int ks = 0; ks < 16; ++ks) {
                const int k0 = ks * 32;
                bf16x8 bf = *(const bf16x8*)&xpw_l[(size_t)(n0 + rla) * DI + k0 + koff];
                bf16x8 af = *(const bf16x8*)&ub[mt * 16 + rla][k0 + koff];
                acc = __builtin_amdgcn_mfma_f32_16x16x32_bf16(af, bf, acc, 0, 0, 0);
            }
            #pragma unroll
            for (int r = 0; r < 4; ++r) {
                const int m = mt * 16 + lrow + r;
                if (m < LL) dbc[m][n0 + lcol] = acc[r];
            }
        }
        __syncthreads();

        // ---- phase 4: selective scan, thread = channel ----
        {
            const int ch = t;
            float wdt[DR], Av[DS];
            {
                const float* wp = dtw + (size_t)layer * DI * DR + ch * DR;
                #pragma unroll
                for (int q = 0; q < DR / 4; ++q) {
                    float4 v = *(const float4*)&wp[q * 4];
                    wdt[q * 4 + 0] = v.x; wdt[q * 4 + 1] = v.y;
                    wdt[q * 4 + 2] = v.z; wdt[q * 4 + 3] = v.w;
                }
                const float* ap = alog + (size_t)layer * DI * DS + ch * DS;
                #pragma unroll
                for (int q = 0; q < DS / 4; ++q) {
                    float4 v = *(const float4*)&ap[q * 4];
                    Av[q * 4 + 0] = -expf(v.x); Av[q * 4 + 1] = -expf(v.y);
                    Av[q * 4 + 2] = -expf(v.z); Av[q * 4 + 3] = -expf(v.w);
                }
            }
            const float dbias = dtb[layer * DI + ch];
            const float Dd = Dvec[layer * DI + ch];
            float st[DS];
            #pragma unroll
            for (int s = 0; s < DS; ++s) st[s] = 0.f;

            #pragma unroll 2
            for (int l = 0; l < LL; ++l) {
                float d0 = 0.f, d1 = 0.f, d2 = 0.f, d3 = 0.f;
                #pragma unroll
                for (int r = 0; r < 4; ++r) {
                    d0 += wdt[r]      * dbc[l][r];
                    d1 += wdt[4 + r]  * dbc[l][4 + r];
                    d2 += wdt[8 + r]  * dbc[l][8 + r];
                    d3 += wdt[12 + r] * dbc[l][12 + r];
                }
                const float d = softplusf_(((d0 + d1) + (d2 + d3)) + dbias);
                const float uu = __bfloat162float(ub[l][ch]);
                const float du = d * uu;
                float yv = 0.f;
                #pragma unroll
                for (int s = 0; s < DS; ++s) {
                    st[s] = __expf(d * Av[s]) * st[s] + du * dbc[l][DR + s];
                    yv += st[s] * dbc[l][DR + DS + s];
                }
                const float g = siluf_(__bfloat162float(zb[l][ch]));
                xb[l][ch] = __float2bfloat16((yv + uu * Dd) * g);   // y reuses xb
            }
        }
        __syncthreads();

        // ---- phase 5: h += y @ opw^T  (M=28->32, N=256, K=512) ----
        for (int idx = wave; idx < 32; idx += 8) {
            const int mt = idx & 1;
            const int nt = idx >> 1;
            const int n0 = nt * 16;
            f32x4 acc = {};
            #pragma unroll
            for (int ks = 0; ks < 16; ++ks) {
                const int k0 = ks * 32;
                bf16x8 bf = *(const bf16x8*)&opw_l[(size_t)(n0 + rla) * DI + k0 + koff];
                bf16x8 af = *(const bf16x8*)&xb[mt * 16 + rla][k0 + koff];
                acc = __builtin_amdgcn_mfma_f32_16x16x32_bf16(af, bf, acc, 0, 0, 0);
            }
            #pragma unroll
            for (int r = 0; r < 4; ++r) {
                const int m = mt * 16 + lrow + r;
                if (m < LL) {
                    const int n = n0 + lcol;
                    const float v = h32[m][n] + acc[r];
                    h32[m][n] = v;
                    hbf[m][n] = __float2bfloat16(v);
                }
            }
        }
        __syncthreads();
    }

    // ---- pool + classifier ----
    if (t < DM) {
        float p = 0.f;
        for (int l = 0; l < LL; ++l) p += h32[l][t];
        pooled[t] = p * (1.0f / LL);
    }
    __syncthreads();
    if (t < NOUT) {
        float a0 = 0.f, a1 = 0.f, a2 = 0.f, a3 = 0.f;
        const float* cw = clsw + t * DM;
        for (int k = 0; k < DM; k += 4) {
            a0 += pooled[k + 0] * cw[k + 0];
            a1 += pooled[k + 1] * cw[k + 1];
            a2 += pooled[k + 2] * cw[k + 2];
            a3 += pooled[k + 3] * cw[k + 3];
        }
        out[b * NOUT + t] = (a0 + a1) + (a2 + a3);
    }
}

extern "C" void kernel_launch(void* const* d_in, const int* in_sizes, int n_in,
                              void* d_out, int out_size, void* d_ws, size_t ws_size,
                              hipStream_t stream) {
    const float* x       = (const float*)d_in[0];
    const float* ipw     = (const float*)d_in[1];
    const float* inw     = (const float*)d_in[2];
    const float* convw   = (const float*)d_in[3];
    const float* convb   = (const float*)d_in[4];
    const float* xpw     = (const float*)d_in[5];
    const float* dtw     = (const float*)d_in[6];
    const float* dtb     = (const float*)d_in[7];
    const float* alog    = (const float*)d_in[8];
    const float* Dvec    = (const float*)d_in[9];
    const float* opw     = (const float*)d_in[10];
    const float* clsw    = (const float*)d_in[11];
    float* out = (float*)d_out;

    __hip_bfloat16* inwb = (__hip_bfloat16*)d_ws;
    __hip_bfloat16* opwb = inwb + N_INW;
    __hip_bfloat16* xpwb = opwb + N_OPW;

    hipLaunchKernelGGL(cast_weights, dim3((N_INW + N_OPW + N_XPW) / 1024), dim3(256), 0, stream,
                       inw, opw, xpw, inwb, opwb, xpwb);

    hipLaunchKernelGGL(mamba_mega, dim3(BB), dim3(512), 0, stream,
                       x, ipw, convw, convb, dtw, dtb, alog, Dvec, clsw,
                       inwb, opwb, xpwb, out);
}

// Round 10
// 352.363 us; speedup vs baseline: 1.0033x; 1.0033x over previous
//
#include <hip/hip_runtime.h>
#include <hip/hip_bf16.h>
#include <cstdint>

#define BB 128
#define LL 28
#define FF 28
#define DM 256
#define DI 512
#define DS 16
#define DR 16
#define KK 3
#define NLAYER 5
#define NOUT 10
#define NDBC (DR + 2 * DS)  // 48

#define N_INW (NLAYER * 2 * DI * DM)   // 1310720
#define N_OPW (NLAYER * DM * DI)       // 655360
#define N_XPW (NLAYER * NDBC * DI)     // 122880

typedef __attribute__((ext_vector_type(8))) short bf16x8;
typedef __attribute__((ext_vector_type(4))) float f32x4;

__device__ __forceinline__ float sigmoidf_(float x) { return 1.0f / (1.0f + __expf(-x)); }
__device__ __forceinline__ float siluf_(float x) { return x * sigmoidf_(x); }
__device__ __forceinline__ float softplusf_(float x) {
    return (x > 20.0f) ? x : log1pf(expf(x));
}

// ---------------- weight cast fp32 -> bf16 (one kernel, all layers) ----------------
__global__ void cast_weights(const float* __restrict__ inw, const float* __restrict__ opw,
                             const float* __restrict__ xpw,
                             __hip_bfloat16* __restrict__ inwb, __hip_bfloat16* __restrict__ opwb,
                             __hip_bfloat16* __restrict__ xpwb) {
    int i = (blockIdx.x * 256 + threadIdx.x) * 4;
    const float* s; __hip_bfloat16* d; int off;
    if (i < N_INW) { s = inw; d = inwb; off = i; }
    else if (i < N_INW + N_OPW) { s = opw; d = opwb; off = i - N_INW; }
    else if (i < N_INW + N_OPW + N_XPW) { s = xpw; d = xpwb; off = i - N_INW - N_OPW; }
    else return;
    float4 v = *(const float4*)&s[off];
    d[off + 0] = __float2bfloat16(v.x);
    d[off + 1] = __float2bfloat16(v.y);
    d[off + 2] = __float2bfloat16(v.z);
    d[off + 3] = __float2bfloat16(v.w);
}

// ---------------- whole-network megakernel: 1 block = 1 batch element ----------------
// 512 threads = 8 waves. Activations LDS-resident; weights streamed from L2.
// A-fragments register-hoisted (invariant across n-tiles); scan reads float4.
__global__ __launch_bounds__(512, 2) void mamba_mega(
        const float* __restrict__ x,        // [BB][LL][FF]
        const float* __restrict__ ipw,      // [DM][FF]
        const float* __restrict__ convw,    // [NL][DI][KK]
        const float* __restrict__ convb,    // [NL][DI]
        const float* __restrict__ dtw,      // [NL][DI][DR]
        const float* __restrict__ dtb,      // [NL][DI]
        const float* __restrict__ alog,     // [NL][DI][DS]
        const float* __restrict__ Dvec,     // [NL][DI]
        const float* __restrict__ clsw,     // [NOUT][DM]
        const __hip_bfloat16* __restrict__ inwb,  // [NL][2*DI][DM]
        const __hip_bfloat16* __restrict__ opwb,  // [NL][DM][DI]
        const __hip_bfloat16* __restrict__ xpwb,  // [NL][NDBC][DI]
        float* __restrict__ out)            // [BB][NOUT]
{
    __shared__ float h32[LL][DM];                          // fp32 residual
    __shared__ __align__(16) __hip_bfloat16 hbf[32][264];  // bf16 h
    __shared__ __align__(16) __hip_bfloat16 xb[32][520];   // conv input, then y
    __shared__ __align__(16) __hip_bfloat16 zb[LL][DI];    // gate input
    __shared__ __align__(16) __hip_bfloat16 ub[32][520];   // conv output
    __shared__ float dbc[32][NDBC];
    __shared__ float sx[LL][FF];
    __shared__ float pooled[DM];

    const int b = blockIdx.x;
    const int t = threadIdx.x;      // 0..511
    const int wave = t >> 6;
    const int lane = t & 63;
    const int rla = lane & 15;              // fragment row (A and B)
    const int koff = (lane >> 4) * 8;       // fragment k offset
    const int lrow = (lane >> 4) * 4;       // C/D row base
    const int lcol = lane & 15;             // C/D col

    // zero M-pad rows (28..31); they stay zero for the whole kernel
    for (int i = t; i < 4 * 264; i += 512) hbf[28 + i / 264][i % 264] = __float2bfloat16(0.f);
    for (int i = t; i < 4 * 520; i += 512) {
        xb[28 + i / 520][i % 520] = __float2bfloat16(0.f);
        ub[28 + i / 520][i % 520] = __float2bfloat16(0.f);
    }
    for (int i = t; i < LL * FF / 4; i += 512)
        *(float4*)&sx[0][i * 4] = *(const float4*)&x[(size_t)b * LL * FF + i * 4];
    __syncthreads();

    // ---- input projection: h[l][n] = sum_f x[l][f] * ipw[n][f] ----
    if (t < DM) {
        const int n = t;
        float w[FF];
        #pragma unroll
        for (int q = 0; q < FF / 4; ++q) {
            float4 v = *(const float4*)&ipw[n * FF + q * 4];
            w[q * 4 + 0] = v.x; w[q * 4 + 1] = v.y; w[q * 4 + 2] = v.z; w[q * 4 + 3] = v.w;
        }
        for (int l = 0; l < LL; ++l) {
            float a0 = 0.f, a1 = 0.f, a2 = 0.f, a3 = 0.f;
            #pragma unroll
            for (int f = 0; f < FF; f += 4) {
                a0 += w[f + 0] * sx[l][f + 0];
                a1 += w[f + 1] * sx[l][f + 1];
                a2 += w[f + 2] * sx[l][f + 2];
                a3 += w[f + 3] * sx[l][f + 3];
            }
            float v = (a0 + a1) + (a2 + a3);
            h32[l][n] = v;
            hbf[l][n] = __float2bfloat16(v);
        }
    }
    __syncthreads();

    for (int layer = 0; layer < NLAYER; ++layer) {
        const __hip_bfloat16* inw_l = inwb + (size_t)layer * 2 * DI * DM;
        const __hip_bfloat16* opw_l = opwb + (size_t)layer * DM * DI;
        const __hip_bfloat16* xpw_l = xpwb + (size_t)layer * NDBC * DI;

        // ---- phase 1: xz = h @ inw^T  (M=32, N=1024, K=256) ----
        {
            // hoist A-fragments once per wave (invariant over n-tiles)
            bf16x8 af0[8], af1[8];
            #pragma unroll
            for (int ks = 0; ks < 8; ++ks) {
                af0[ks] = *(const bf16x8*)&hbf[rla][ks * 32 + koff];
                af1[ks] = *(const bf16x8*)&hbf[16 + rla][ks * 32 + koff];
            }
            for (int nt = wave; nt < 64; nt += 8) {
                const int n0 = nt * 16;
                f32x4 acc0 = {}, acc1 = {};
                #pragma unroll
                for (int ks = 0; ks < 8; ++ks) {
                    bf16x8 bf = *(const bf16x8*)&inw_l[(size_t)(n0 + rla) * DM + ks * 32 + koff];
                    acc0 = __builtin_amdgcn_mfma_f32_16x16x32_bf16(af0[ks], bf, acc0, 0, 0, 0);
                    acc1 = __builtin_amdgcn_mfma_f32_16x16x32_bf16(af1[ks], bf, acc1, 0, 0, 0);
                }
                const int n = n0 + lcol;
                #pragma unroll
                for (int r = 0; r < 4; ++r) {
                    const int m0 = lrow + r;
                    const int m1 = 16 + lrow + r;
                    if (n < DI) {
                        xb[m0][n] = __float2bfloat16(acc0[r]);
                        if (m1 < LL) xb[m1][n] = __float2bfloat16(acc1[r]);
                    } else {
                        zb[m0][n - DI] = __float2bfloat16(acc0[r]);
                        if (m1 < LL) zb[m1][n - DI] = __float2bfloat16(acc1[r]);
                    }
                }
            }
        }
        __syncthreads();

        // ---- phase 2: u = silu(conv(xb)+cb), thread = channel ----
        {
            const int ch = t;
            const float c0 = convw[(size_t)layer * DI * KK + ch * KK + 0];
            const float c1 = convw[(size_t)layer * DI * KK + ch * KK + 1];
            const float c2 = convw[(size_t)layer * DI * KK + ch * KK + 2];
            const float cbv = convb[layer * DI + ch];
            float xm2 = 0.f, xm1 = 0.f;
            #pragma unroll 4
            for (int l = 0; l < LL; ++l) {
                const float x0 = __bfloat162float(xb[l][ch]);
                const float acc = cbv + c0 * xm2 + c1 * xm1 + c2 * x0;
                xm2 = xm1; xm1 = x0;
                ub[l][ch] = __float2bfloat16(siluf_(acc));
            }
        }
        __syncthreads();

        // ---- phase 3: dbc = u @ xpw^T  (M=32, N=48, K=512), waves 0..5 ----
        if (wave < 6) {
            const int mt = wave & 1;
            const int nt = wave >> 1;
            const int n0 = nt * 16;
            f32x4 acc = {};
            #pragma unroll
            for (int ks = 0; ks < 16; ++ks) {
                bf16x8 bf = *(const bf16x8*)&xpw_l[(size_t)(n0 + rla) * DI + ks * 32 + koff];
                bf16x8 af = *(const bf16x8*)&ub[mt * 16 + rla][ks * 32 + koff];
                acc = __builtin_amdgcn_mfma_f32_16x16x32_bf16(af, bf, acc, 0, 0, 0);
            }
            #pragma unroll
            for (int r = 0; r < 4; ++r) {
                const int m = mt * 16 + lrow + r;
                if (m < LL) dbc[m][n0 + lcol] = acc[r];
            }
        }
        __syncthreads();

        // ---- phase 4: selective scan, thread = channel, float4 LDS reads ----
        {
            const int ch = t;
            float wdt[DR], Av[DS];
            {
                const float* wp = dtw + (size_t)layer * DI * DR + ch * DR;
                #pragma unroll
                for (int q = 0; q < DR / 4; ++q) {
                    float4 v = *(const float4*)&wp[q * 4];
                    wdt[q * 4 + 0] = v.x; wdt[q * 4 + 1] = v.y;
                    wdt[q * 4 + 2] = v.z; wdt[q * 4 + 3] = v.w;
                }
                const float* ap = alog + (size_t)layer * DI * DS + ch * DS;
                #pragma unroll
                for (int q = 0; q < DS / 4; ++q) {
                    float4 v = *(const float4*)&ap[q * 4];
                    Av[q * 4 + 0] = -expf(v.x); Av[q * 4 + 1] = -expf(v.y);
                    Av[q * 4 + 2] = -expf(v.z); Av[q * 4 + 3] = -expf(v.w);
                }
            }
            const float dbias = dtb[layer * DI + ch];
            const float Dd = Dvec[layer * DI + ch];
            float st[DS];
            #pragma unroll
            for (int s = 0; s < DS; ++s) st[s] = 0.f;

            #pragma unroll 2
            for (int l = 0; l < LL; ++l) {
                const float4 q0 = *(const float4*)&dbc[l][0];
                const float4 q1 = *(const float4*)&dbc[l][4];
                const float4 q2 = *(const float4*)&dbc[l][8];
                const float4 q3 = *(const float4*)&dbc[l][12];
                float d0 = wdt[0] * q0.x + wdt[1] * q0.y + wdt[2] * q0.z + wdt[3] * q0.w;
                float d1 = wdt[4] * q1.x + wdt[5] * q1.y + wdt[6] * q1.z + wdt[7] * q1.w;
                float d2 = wdt[8] * q2.x + wdt[9] * q2.y + wdt[10] * q2.z + wdt[11] * q2.w;
                float d3 = wdt[12] * q3.x + wdt[13] * q3.y + wdt[14] * q3.z + wdt[15] * q3.w;
                const float d = softplusf_(((d0 + d1) + (d2 + d3)) + dbias);

                const float uu = __bfloat162float(ub[l][ch]);
                const float du = d * uu;
                const float4 B0 = *(const float4*)&dbc[l][DR + 0];
                const float4 B1 = *(const float4*)&dbc[l][DR + 4];
                const float4 B2 = *(const float4*)&dbc[l][DR + 8];
                const float4 B3 = *(const float4*)&dbc[l][DR + 12];
                const float4 C0 = *(const float4*)&dbc[l][DR + DS + 0];
                const float4 C1 = *(const float4*)&dbc[l][DR + DS + 4];
                const float4 C2 = *(const float4*)&dbc[l][DR + DS + 8];
                const float4 C3 = *(const float4*)&dbc[l][DR + DS + 12];
                float yv = 0.f;
                st[0]  = __expf(d * Av[0])  * st[0]  + du * B0.x;  yv += st[0]  * C0.x;
                st[1]  = __expf(d * Av[1])  * st[1]  + du * B0.y;  yv += st[1]  * C0.y;
                st[2]  = __expf(d * Av[2])  * st[2]  + du * B0.z;  yv += st[2]  * C0.z;
                st[3]  = __expf(d * Av[3])  * st[3]  + du * B0.w;  yv += st[3]  * C0.w;
                st[4]  = __expf(d * Av[4])  * st[4]  + du * B1.x;  yv += st[4]  * C1.x;
                st[5]  = __expf(d * Av[5])  * st[5]  + du * B1.y;  yv += st[5]  * C1.y;
                st[6]  = __expf(d * Av[6])  * st[6]  + du * B1.z;  yv += st[6]  * C1.z;
                st[7]  = __expf(d * Av[7])  * st[7]  + du * B1.w;  yv += st[7]  * C1.w;
                st[8]  = __expf(d * Av[8])  * st[8]  + du * B2.x;  yv += st[8]  * C2.x;
                st[9]  = __expf(d * Av[9])  * st[9]  + du * B2.y;  yv += st[9]  * C2.y;
                st[10] = __expf(d * Av[10]) * st[10] + du * B2.z;  yv += st[10] * C2.z;
                st[11] = __expf(d * Av[11]) * st[11] + du * B2.w;  yv += st[11] * C2.w;
                st[12] = __expf(d * Av[12]) * st[12] + du * B3.x;  yv += st[12] * C3.x;
                st[13] = __expf(d * Av[13]) * st[13] + du * B3.y;  yv += st[13] * C3.y;
                st[14] = __expf(d * Av[14]) * st[14] + du * B3.z;  yv += st[14] * C3.z;
                st[15] = __expf(d * Av[15]) * st[15] + du * B3.w;  yv += st[15] * C3.w;

                const float g = siluf_(__bfloat162float(zb[l][ch]));
                xb[l][ch] = __float2bfloat16((yv + uu * Dd) * g);   // y reuses xb
            }
        }
        __syncthreads();

        // ---- phase 5: h += y @ opw^T  (M=32, N=256, K=512); wave owns fixed mt ----
        {
            const int mt = wave & 1;
            bf16x8 af[16];
            #pragma unroll
            for (int ks = 0; ks < 16; ++ks)
                af[ks] = *(const bf16x8*)&xb[mt * 16 + rla][ks * 32 + koff];
            #pragma unroll
            for (int i = 0; i < 4; ++i) {
                const int nt = (wave >> 1) + i * 4;   // 0..15
                const int n0 = nt * 16;
                f32x4 acc = {};
                #pragma unroll
                for (int ks = 0; ks < 16; ++ks) {
                    bf16x8 bf = *(const bf16x8*)&opw_l[(size_t)(n0 + rla) * DI + ks * 32 + koff];
                    acc = __builtin_amdgcn_mfma_f32_16x16x32_bf16(af[ks], bf, acc, 0, 0, 0);
                }
                #pragma unroll
                for (int r = 0; r < 4; ++r) {
                    const int m = mt * 16 + lrow + r;
                    if (m < LL) {
                        const int n = n0 + lcol;
                        const float v = h32[m][n] + acc[r];
                        h32[m][n] = v;
                        hbf[m][n] = __float2bfloat16(v);
                    }
                }
            }
        }
        __syncthreads();
    }

    // ---- pool + classifier ----
    if (t < DM) {
        float p = 0.f;
        for (int l = 0; l < LL; ++l) p += h32[l][t];
        pooled[t] = p * (1.0f / LL);
    }
    __syncthreads();
    if (t < NOUT) {
        float a0 = 0.f, a1 = 0.f, a2 = 0.f, a3 = 0.f;
        const float* cw = clsw + t * DM;
        for (int k = 0; k < DM; k += 4) {
            a0 += pooled[k + 0] * cw[k + 0];
            a1 += pooled[k + 1] * cw[k + 1];
            a2 += pooled[k + 2] * cw[k + 2];
            a3 += pooled[k + 3] * cw[k + 3];
        }
        out[b * NOUT + t] = (a0 + a1) + (a2 + a3);
    }
}

extern "C" void kernel_launch(void* const* d_in, const int* in_sizes, int n_in,
                              void* d_out, int out_size, void* d_ws, size_t ws_size,
                              hipStream_t stream) {
    const float* x       = (const float*)d_in[0];
    const float* ipw     = (const float*)d_in[1];
    const float* inw     = (const float*)d_in[2];
    const float* convw   = (const float*)d_in[3];
    const float* convb   = (const float*)d_in[4];
    const float* xpw     = (const float*)d_in[5];
    const float* dtw     = (const float*)d_in[6];
    const float* dtb     = (const float*)d_in[7];
    const float* alog    = (const float*)d_in[8];
    const float* Dvec    = (const float*)d_in[9];
    const float* opw     = (const float*)d_in[10];
    const float* clsw    = (const float*)d_in[11];
    float* out = (float*)d_out;

    __hip_bfloat16* inwb = (__hip_bfloat16*)d_ws;
    __hip_bfloat16* opwb = inwb + N_INW;
    __hip_bfloat16* xpwb = opwb + N_OPW;

    hipLaunchKernelGGL(cast_weights, dim3((N_INW + N_OPW + N_XPW) / 1024), dim3(256), 0, stream,
                       inw, opw, xpw, inwb, opwb, xpwb);

    hipLaunchKernelGGL(mamba_mega, dim3(BB), dim3(512), 0, stream,
                       x, ipw, convw, convb, dtw, dtb, alog, Dvec, clsw,
                       inwb, opwb, xpwb, out);
}